// Round 14
// baseline (28.240 us; speedup 1.0000x reference)
//
#include <hip/hip_runtime.h>
#include <math.h>

#define RES 96
#define NV 97
#define NV2 (NV * NV)                      // 9409
#define NCELLS (RES * RES * RES)           // 884736
#define NBLK 3456                          // 24*24*6 tiles of 4x4x16
#define MAX_DISP (2.0f / 96.0f / 4.0f)
#define NVT 425                            // 5*5*17 tile vertices

typedef float f32x4 __attribute__((ext_vector_type(4)));
typedef float f32x4u __attribute__((ext_vector_type(4), aligned(4)));
typedef float f32x2u __attribute__((ext_vector_type(2), aligned(4)));

__device__ __forceinline__ float grid_coord(int a) {
    // linspace(-0.5,0.5,97)[a] * 2  ==  a/48 - 1
    return fmaf((float)a, 1.0f / 48.0f, -1.0f);
}

__device__ __forceinline__ float fast_tanh(float x) {
    x = fminf(fmaxf(x, -15.f), 15.f);
    const float e = __expf(2.f * x);
    return (e - 1.f) * __builtin_amdgcn_rcpf(e + 1.f);
}

// R13 structure + register-pressure attack: p[12][3] (36 VGPR) eliminated by
// a two-pass edge loop — pass 2 RECOMPUTES p_e from still-live s/x/alpha
// (~120 extra VALU/thread, trades ~1.3us VALU for +2-3 blocks/CU residency;
// VGPR was the occupancy cap after R13 moved it off LDS). Weights row loads
// vectorized 21 dwords -> 5x dwordx4 (4B-aligned) + 1.
// Hard-won constraints: no nt hints (R12: L3 refetch), no same-address atomic
// tails (R6/R7: coherence-point serialization), no forced VGPR bounds (R11:
// scratch spill), 256-thread 4x4x16 tile (R10: 128-thread regressed).
__global__ __launch_bounds__(256) void flexi_fused(
    const float* __restrict__ sdf,
    const float* __restrict__ deform,
    const float* __restrict__ weights,
    float* __restrict__ out_vd,
    float* __restrict__ partial)
{
    __shared__ float4 vs4[NVT];            // (x,y,z,sdf) per tile vertex, 6.8KB
    __shared__ float  sm[8];

    const int t = threadIdx.x;
    // chunked XCD swizzle: 8 XCDs x 432 contiguous tiles (bijective: 3456=8*432)
    const int bidx = (blockIdx.x & 7) * 432 + (blockIdx.x >> 3);
    const int bi = bidx / 144;             // i-tile (0..23)
    const int rb = bidx - bi * 144;
    const int bj = rb / 6;                 // j-tile (0..23)
    const int bk = rb - bj * 6;            // k-tile (0..5)

    // ---- cell id + weights row (5x dwordx4 + 1, issued FIRST) ----
    const int ti = t >> 6;
    const int tj = (t >> 4) & 3;
    const int tk = t & 15;
    const int c = (4 * bi + ti) * 9216 + (4 * bj + tj) * 96 + 16 * bk + tk;
    const float* wrow = weights + (size_t)c * 21;
    float myw[21];                         // beta[0..11], alpha[12..19], gamma[20]
    {
        const f32x4u* wv = reinterpret_cast<const f32x4u*>(wrow);
        const f32x4u w0 = wv[0], w1 = wv[1], w2 = wv[2], w3 = wv[3], w4 = wv[4];
        myw[0]=w0.x;  myw[1]=w0.y;  myw[2]=w0.z;  myw[3]=w0.w;
        myw[4]=w1.x;  myw[5]=w1.y;  myw[6]=w1.z;  myw[7]=w1.w;
        myw[8]=w2.x;  myw[9]=w2.y;  myw[10]=w2.z; myw[11]=w2.w;
        myw[12]=w3.x; myw[13]=w3.y; myw[14]=w3.z; myw[15]=w3.w;
        myw[16]=w4.x; myw[17]=w4.y; myw[18]=w4.z; myw[19]=w4.w;
        myw[20]=wrow[20];
    }

    // ---- stage tile vertices: (deformed pos, sdf) as float4 ----
    #pragma unroll
    for (int it = 0; it < 2; ++it) {
        const int u = t + it * 256;
        if (u < NVT) {
            const int a  = u / 85;             // 0..4
            const int r  = u - a * 85;
            const int b  = r / 17;             // 0..4
            const int cc = r - b * 17;         // 0..16
            const int gv = (4 * bi + a) * NV2 + (4 * bj + b) * NV + 16 * bk + cc;
            const float* dp = deform + (size_t)gv * 3;
            const f32x2u d01 = *reinterpret_cast<const f32x2u*>(dp);
            const float  d2  = dp[2];
            float4 vv;
            vv.x = grid_coord(4 * bi + a)   + MAX_DISP * fast_tanh(d01.x);
            vv.y = grid_coord(4 * bj + b)   + MAX_DISP * fast_tanh(d01.y);
            vv.z = grid_coord(16 * bk + cc) + MAX_DISP * fast_tanh(d2);
            vv.w = sdf[gv];
            vs4[u] = vv;
        }
    }
    __syncthreads();

    // ---- per-cell corners from LDS ----
    const int vbase = ti * 85 + tj * 17 + tk;
    const int OFF[8] = {0, 85, 17, 102, 1, 86, 18, 103};   // reference corner order

    float s[8], x[8][3];
    #pragma unroll
    for (int k = 0; k < 8; ++k) {
        const float4 vv = vs4[vbase + OFF[k]];
        x[k][0] = vv.x; x[k][1] = vv.y; x[k][2] = vv.z;
        s[k] = vv.w;
    }

    const int EA[12] = {0, 1, 4, 0, 2, 3, 6, 2, 2, 3, 7, 6};
    const int EB[12] = {1, 5, 5, 4, 3, 7, 7, 6, 0, 1, 5, 4};

    // ---- pass 1: accumulate centroid (no p[] storage) ----
    float wsum = 0.f, vnum0 = 0.f, vnum1 = 0.f, vnum2 = 0.f;
    int   ncross = 0;
    #pragma unroll
    for (int e = 0; e < 12; ++e) {
        const int a = EA[e], b = EB[e];
        const float sa = s[a], sb = s[b];
        const bool cr = (sa > 0.f) != (sb > 0.f);
        const float ta = myw[12 + a] * sb;
        const float tb = myw[12 + b] * sa;
        // den guard keeps p finite (w=0 masks its value, but 0*inf = NaN)
        const float den = cr ? (ta - tb) : 1.0f;
        const float inv = __builtin_amdgcn_rcpf(den);
        const float p0 = (ta * x[a][0] - tb * x[b][0]) * inv;
        const float p1 = (ta * x[a][1] - tb * x[b][1]) * inv;
        const float p2 = (ta * x[a][2] - tb * x[b][2]) * inv;
        const float w = cr ? myw[e] : 0.f;
        wsum  += w;
        vnum0 += w * p0;
        vnum1 += w * p1;
        vnum2 += w * p2;
        ncross += cr ? 1 : 0;
    }

    const bool surf = (ncross > 0);
    const float invden = __builtin_amdgcn_rcpf(surf ? wsum : 1.0f);
    float vd0 = vnum0 * invden;
    float vd1 = vnum1 * invden;
    float vd2 = vnum2 * invden;
    if (!surf) { vd0 = 0.f; vd1 = 0.f; vd2 = 0.f; }

    out_vd[(size_t)c * 3 + 0] = vd0;
    out_vd[(size_t)c * 3 + 1] = vd1;
    out_vd[(size_t)c * 3 + 2] = vd2;

    // ---- pass 2: deviation, RECOMPUTING p_e (frees 36 VGPRs of p[]) ----
    float devsum = 0.f;
    #pragma unroll
    for (int e = 0; e < 12; ++e) {
        const int a = EA[e], b = EB[e];
        const float sa = s[a], sb = s[b];
        const bool cr = (sa > 0.f) != (sb > 0.f);
        const float ta = myw[12 + a] * sb;
        const float tb = myw[12 + b] * sa;
        const float den = cr ? (ta - tb) : 1.0f;
        const float inv = __builtin_amdgcn_rcpf(den);
        const float p0 = (ta * x[a][0] - tb * x[b][0]) * inv;
        const float p1 = (ta * x[a][1] - tb * x[b][1]) * inv;
        const float p2 = (ta * x[a][2] - tb * x[b][2]) * inv;
        const float d0 = p0 - vd0;
        const float d1 = p1 - vd1;
        const float d2 = p2 - vd2;
        const float nrm = __builtin_amdgcn_sqrtf(d0 * d0 + d1 * d1 + d2 * d2 + 1e-12f);
        devsum += cr ? nrm : 0.f;
    }
    const float dev = devsum * __builtin_amdgcn_rcpf(fmaxf((float)ncross, 1.0f));
    float regc = surf ? dev * myw[20] : 0.f;
    float cnt  = surf ? 1.0f : 0.f;

    #pragma unroll
    for (int off = 32; off > 0; off >>= 1) {
        regc += __shfl_down(regc, off);
        cnt  += __shfl_down(cnt, off);
    }
    const int wid = t >> 6;
    if ((t & 63) == 0) { sm[wid] = regc; sm[4 + wid] = cnt; }
    __syncthreads();
    if (t == 0) {
        partial[bidx]        = sm[0] + sm[1] + sm[2] + sm[3];
        partial[NBLK + bidx] = sm[4] + sm[5] + sm[6] + sm[7];
    }
}

__global__ __launch_bounds__(1024) void flexi_reduce(
    const float* __restrict__ partial, float* __restrict__ reg_out)
{
    float a = 0.f, b = 0.f;
    for (int i = threadIdx.x; i < NBLK; i += 1024) {
        a += partial[i];
        b += partial[NBLK + i];
    }
    #pragma unroll
    for (int off = 32; off > 0; off >>= 1) {
        a += __shfl_down(a, off);
        b += __shfl_down(b, off);
    }
    __shared__ float sm[32];
    const int wid = threadIdx.x >> 6;      // 16 waves
    if ((threadIdx.x & 63) == 0) { sm[wid] = a; sm[16 + wid] = b; }
    __syncthreads();
    if (threadIdx.x == 0) {
        float num = 0.f, den = 0.f;
        #pragma unroll
        for (int i = 0; i < 16; ++i) { num += sm[i]; den += sm[16 + i]; }
        reg_out[0] = num / fmaxf(den, 1.0f);
    }
}

extern "C" void kernel_launch(void* const* d_in, const int* in_sizes, int n_in,
                              void* d_out, int out_size, void* d_ws, size_t ws_size,
                              hipStream_t stream)
{
    // inputs: verts(analytic), indices(analytic), sdf, deform, weights
    const float* sdf     = (const float*)d_in[2];
    const float* deform  = (const float*)d_in[3];
    const float* weights = (const float*)d_in[4];
    float* out     = (float*)d_out;
    float* partial = (float*)d_ws;     // 2*NBLK floats, all rewritten each call

    flexi_fused<<<NBLK, 256, 0, stream>>>(sdf, deform, weights, out, partial);
    flexi_reduce<<<1, 1024, 0, stream>>>(partial, out + (size_t)NCELLS * 3);
}

// Round 15
// 25.918 us; speedup vs baseline: 1.0896x; 1.0896x over previous
//
#include <hip/hip_runtime.h>
#include <math.h>

#define RES 96
#define NV 97
#define NV2 (NV * NV)                      // 9409
#define NCELLS (RES * RES * RES)           // 884736
#define NBLK 3456                          // 24*24*6 tiles of 4x4x16
#define MAX_DISP (2.0f / 96.0f / 4.0f)
#define NVT 425                            // 5*5*17 tile vertices

typedef float f32x2u __attribute__((ext_vector_type(2), aligned(4)));

__device__ __forceinline__ float grid_coord(int a) {
    // linspace(-0.5,0.5,97)[a] * 2  ==  a/48 - 1
    return fmaf((float)a, 1.0f / 48.0f, -1.0f);
}

__device__ __forceinline__ float fast_tanh(float x) {
    x = fminf(fmaxf(x, -15.f), 15.f);
    const float e = __expf(2.f * x);
    return (e - 1.f) * __builtin_amdgcn_rcpf(e + 1.f);
}

// R13 structure (best: 25.5us) with ONE change: the 21 per-thread weight-row
// loads are issued AFTER the staging loop's loads+LDS writes (VMEM returns
// are consumed in issue order via vmcnt — weights issued first forced every
// wave to drain 21 not-yet-needed loads before the first tanh of the
// block-critical staging->barrier chain; issued last, they stay in flight
// until after the barrier).
// Hard-won constraints: single-pass edge loop with p[] in regs (R14's
// recompute cost 2.7us), no nt hints (R12: L3 refetch), no same-address
// atomic tails (R6/R7), no forced VGPR bounds (R11: spill), 256-thread
// 4x4x16 tile (R10: 128-thread regressed).
__global__ __launch_bounds__(256) void flexi_fused(
    const float* __restrict__ sdf,
    const float* __restrict__ deform,
    const float* __restrict__ weights,
    float* __restrict__ out_vd,
    float* __restrict__ partial)
{
    __shared__ float4 vs4[NVT];            // (x,y,z,sdf) per tile vertex, 6.8KB
    __shared__ float  sm[8];

    const int t = threadIdx.x;
    // chunked XCD swizzle: 8 XCDs x 432 contiguous tiles (bijective: 3456=8*432)
    const int bidx = (blockIdx.x & 7) * 432 + (blockIdx.x >> 3);
    const int bi = bidx / 144;             // i-tile (0..23)
    const int rb = bidx - bi * 144;
    const int bj = rb / 6;                 // j-tile (0..23)
    const int bk = rb - bj * 6;            // k-tile (0..5)

    // ---- stage tile vertices: (deformed pos, sdf) as float4 — FIRST ----
    #pragma unroll
    for (int it = 0; it < 2; ++it) {
        const int u = t + it * 256;
        if (u < NVT) {
            const int a  = u / 85;             // 0..4
            const int r  = u - a * 85;
            const int b  = r / 17;             // 0..4
            const int cc = r - b * 17;         // 0..16
            const int gv = (4 * bi + a) * NV2 + (4 * bj + b) * NV + 16 * bk + cc;
            const float* dp = deform + (size_t)gv * 3;
            const f32x2u d01 = *reinterpret_cast<const f32x2u*>(dp);
            const float  d2  = dp[2];
            float4 vv;
            vv.x = grid_coord(4 * bi + a)   + MAX_DISP * fast_tanh(d01.x);
            vv.y = grid_coord(4 * bj + b)   + MAX_DISP * fast_tanh(d01.y);
            vv.z = grid_coord(16 * bk + cc) + MAX_DISP * fast_tanh(d2);
            vv.w = sdf[gv];
            vs4[u] = vv;
        }
    }

    // ---- weights row loads issued AFTER staging (in flight across barrier) ----
    const int ti = t >> 6;
    const int tj = (t >> 4) & 3;
    const int tk = t & 15;
    const int c = (4 * bi + ti) * 9216 + (4 * bj + tj) * 96 + 16 * bk + tk;
    const float* wrow = weights + (size_t)c * 21;
    float myw[21];                         // beta[0..11], alpha[12..19], gamma[20]
    #pragma unroll
    for (int e = 0; e < 21; ++e) myw[e] = wrow[e];

    __syncthreads();

    // ---- per-cell corners from LDS ----
    const int vbase = ti * 85 + tj * 17 + tk;
    const int OFF[8] = {0, 85, 17, 102, 1, 86, 18, 103};   // reference corner order

    float s[8], x[8][3];
    #pragma unroll
    for (int k = 0; k < 8; ++k) {
        const float4 vv = vs4[vbase + OFF[k]];
        x[k][0] = vv.x; x[k][1] = vv.y; x[k][2] = vv.z;
        s[k] = vv.w;
    }

    const int EA[12] = {0, 1, 4, 0, 2, 3, 6, 2, 2, 3, 7, 6};
    const int EB[12] = {1, 5, 5, 4, 3, 7, 7, 6, 0, 1, 5, 4};

    float p[12][3];
    bool  cross[12];
    float wsum = 0.f, vnum0 = 0.f, vnum1 = 0.f, vnum2 = 0.f;
    int   ncross = 0;
    #pragma unroll
    for (int e = 0; e < 12; ++e) {
        const int a = EA[e], b = EB[e];
        const float sa = s[a], sb = s[b];
        const bool cr = (sa > 0.f) != (sb > 0.f);
        cross[e] = cr;
        const float ta = myw[12 + a] * sb;
        const float tb = myw[12 + b] * sa;
        // den guard keeps p finite (w=0 masks its value, but 0*inf = NaN)
        const float den = cr ? (ta - tb) : 1.0f;
        const float inv = __builtin_amdgcn_rcpf(den);
        const float p0 = (ta * x[a][0] - tb * x[b][0]) * inv;
        const float p1 = (ta * x[a][1] - tb * x[b][1]) * inv;
        const float p2 = (ta * x[a][2] - tb * x[b][2]) * inv;
        p[e][0] = p0; p[e][1] = p1; p[e][2] = p2;
        const float w = cr ? myw[e] : 0.f;
        wsum  += w;
        vnum0 += w * p0;
        vnum1 += w * p1;
        vnum2 += w * p2;
        ncross += cr ? 1 : 0;
    }

    const bool surf = (ncross > 0);
    const float invden = __builtin_amdgcn_rcpf(surf ? wsum : 1.0f);
    float vd0 = vnum0 * invden;
    float vd1 = vnum1 * invden;
    float vd2 = vnum2 * invden;
    if (!surf) { vd0 = 0.f; vd1 = 0.f; vd2 = 0.f; }

    out_vd[(size_t)c * 3 + 0] = vd0;
    out_vd[(size_t)c * 3 + 1] = vd1;
    out_vd[(size_t)c * 3 + 2] = vd2;

    float devsum = 0.f;
    #pragma unroll
    for (int e = 0; e < 12; ++e) {
        const float d0 = p[e][0] - vd0;
        const float d1 = p[e][1] - vd1;
        const float d2 = p[e][2] - vd2;
        const float nrm = __builtin_amdgcn_sqrtf(d0 * d0 + d1 * d1 + d2 * d2 + 1e-12f);
        devsum += cross[e] ? nrm : 0.f;
    }
    const float dev = devsum * __builtin_amdgcn_rcpf(fmaxf((float)ncross, 1.0f));
    float regc = surf ? dev * myw[20] : 0.f;
    float cnt  = surf ? 1.0f : 0.f;

    #pragma unroll
    for (int off = 32; off > 0; off >>= 1) {
        regc += __shfl_down(regc, off);
        cnt  += __shfl_down(cnt, off);
    }
    const int wid = t >> 6;
    if ((t & 63) == 0) { sm[wid] = regc; sm[4 + wid] = cnt; }
    __syncthreads();
    if (t == 0) {
        partial[bidx]        = sm[0] + sm[1] + sm[2] + sm[3];
        partial[NBLK + bidx] = sm[4] + sm[5] + sm[6] + sm[7];
    }
}

__global__ __launch_bounds__(1024) void flexi_reduce(
    const float* __restrict__ partial, float* __restrict__ reg_out)
{
    float a = 0.f, b = 0.f;
    for (int i = threadIdx.x; i < NBLK; i += 1024) {
        a += partial[i];
        b += partial[NBLK + i];
    }
    #pragma unroll
    for (int off = 32; off > 0; off >>= 1) {
        a += __shfl_down(a, off);
        b += __shfl_down(b, off);
    }
    __shared__ float sm[32];
    const int wid = threadIdx.x >> 6;      // 16 waves
    if ((threadIdx.x & 63) == 0) { sm[wid] = a; sm[16 + wid] = b; }
    __syncthreads();
    if (threadIdx.x == 0) {
        float num = 0.f, den = 0.f;
        #pragma unroll
        for (int i = 0; i < 16; ++i) { num += sm[i]; den += sm[16 + i]; }
        reg_out[0] = num / fmaxf(den, 1.0f);
    }
}

extern "C" void kernel_launch(void* const* d_in, const int* in_sizes, int n_in,
                              void* d_out, int out_size, void* d_ws, size_t ws_size,
                              hipStream_t stream)
{
    // inputs: verts(analytic), indices(analytic), sdf, deform, weights
    const float* sdf     = (const float*)d_in[2];
    const float* deform  = (const float*)d_in[3];
    const float* weights = (const float*)d_in[4];
    float* out     = (float*)d_out;
    float* partial = (float*)d_ws;     // 2*NBLK floats, all rewritten each call

    flexi_fused<<<NBLK, 256, 0, stream>>>(sdf, deform, weights, out, partial);
    flexi_reduce<<<1, 1024, 0, stream>>>(partial, out + (size_t)NCELLS * 3);
}